// Round 2
// baseline (42155.832 us; speedup 1.0000x reference)
//
#include <hip/hip_runtime.h>
#include <math.h>

// Problem constants
#define B  64
#define T  1024
#define I  512
#define O  512
#define NZ 2048      // 4*O
#define K  1024      // I + O
#define EPS 1e-5f

// Persistent-kernel geometry
#define GRID   256
#define NGROUP 16
#define GSIZE  (GRID / NGROUP)

// Phase-A tiling (identical to validated round-1 zstep)
#define KC 256
#define PAD 4
#define LDS_STRIDE (KC + PAD)

// ---------------------------------------------------------------------------
// K0: zero sync counters, init h,c from init_hx/init_cx
// ---------------------------------------------------------------------------
__global__ __launch_bounds__(256) void init_all(
    const float* __restrict__ init_hx, const float* __restrict__ init_cx,
    float* __restrict__ h, float* __restrict__ c, unsigned* __restrict__ sync) {
  int idx = blockIdx.x * 256 + threadIdx.x;
  if (idx < (NGROUP + 2) * 32) sync[idx] = 0u;
  if (idx < B * O) {
    int o = idx & (O - 1);
    h[idx] = init_hx[o];
    c[idx] = init_cx[o];
  }
}

// ---------------------------------------------------------------------------
// Hierarchical monotonic grid barrier.
// 16 groups of 16 blocks -> group counters -> master counter -> gen.
// Counters are monotonic (no reset races). Release fence before arrival
// makes this block's writes visible device-wide; acquire fence after the
// spin makes other blocks' writes visible to us (cross-XCD L2 handling is
// the compiler's job for agent-scope fences).
// ---------------------------------------------------------------------------
__device__ __forceinline__ void grid_barrier(unsigned* grp_cnt, unsigned* master,
                                             unsigned* gen, unsigned* bar) {
  __syncthreads();
  if (threadIdx.x == 0) {
    __builtin_amdgcn_fence(__ATOMIC_RELEASE, "agent");
    unsigned old = __hip_atomic_fetch_add(grp_cnt, 1u, __ATOMIC_RELAXED,
                                          __HIP_MEMORY_SCOPE_AGENT);
    if (((old + 1u) % GSIZE) == 0u) {
      unsigned old2 = __hip_atomic_fetch_add(master, 1u, __ATOMIC_RELAXED,
                                             __HIP_MEMORY_SCOPE_AGENT);
      if (((old2 + 1u) % NGROUP) == 0u) {
        __hip_atomic_fetch_add(gen, 1u, __ATOMIC_RELAXED,
                               __HIP_MEMORY_SCOPE_AGENT);
      }
    }
    unsigned target = ++(*bar);
    while (__hip_atomic_load(gen, __ATOMIC_RELAXED,
                             __HIP_MEMORY_SCOPE_AGENT) < target) {
      __builtin_amdgcn_s_sleep(1);
    }
    __builtin_amdgcn_fence(__ATOMIC_ACQUIRE, "agent");
  }
  __syncthreads();
}

// ---------------------------------------------------------------------------
// Persistent kernel: whole T-loop. 256 blocks x 256 threads, 1 block/CU.
// Per step: phase A (z = cat(x_t,h) @ W^T, same tiling as round-1 zstep),
// barrier, phase B (LN + gates + c/h update, blocks 0..63), barrier.
// ---------------------------------------------------------------------------
__global__ __launch_bounds__(256) void lstm_persistent(
    const float* __restrict__ x, const float* __restrict__ W,
    const float* __restrict__ gamma, const float* __restrict__ beta,
    float* __restrict__ h, float* __restrict__ c, float* __restrict__ z,
    float* __restrict__ out, unsigned* __restrict__ sync) {

  __shared__ float cat[B * LDS_STRIDE];
  __shared__ float red1[4], red2[4];

  const int tid  = threadIdx.x;
  const int wv   = tid >> 6;
  const int lane = tid & 63;
  const int blk  = blockIdx.x;

  unsigned* grp_cnt = sync + (blk / GSIZE) * 32;
  unsigned* master  = sync + NGROUP * 32;
  unsigned* gen     = sync + (NGROUP + 1) * 32;
  unsigned  bar     = 0;

  const int n0 = blk * 8;
  const int j0 = 2 * wv, j1 = 2 * wv + 1;
  const float* __restrict__ wrow0 = W + (size_t)(n0 + j0) * K;
  const float* __restrict__ wrow1 = W + (size_t)(n0 + j1) * K;

  for (int t = 0; t < T; ++t) {
    // ---------------- phase A: z = cat(x_t, h) @ W^T ----------------
    float acc0 = 0.f, acc1 = 0.f;
    for (int ch = 0; ch < 4; ++ch) {
      const int base_k = ch * KC;
      #pragma unroll
      for (int i = 0; i < 16; ++i) {
        int idx = tid + i * 256;
        int b   = idx >> 6;
        int k4  = idx & 63;
        float4 v;
        if (ch < 2) {
          v = *(const float4*)(x + ((size_t)b * T + t) * I + base_k + k4 * 4);
        } else {
          v = *(const float4*)(h + b * O + (base_k - I) + k4 * 4);
        }
        *(float4*)&cat[b * LDS_STRIDE + k4 * 4] = v;
      }
      __syncthreads();

      const float* cr  = &cat[lane * LDS_STRIDE];
      const float* wr0 = wrow0 + base_k;
      const float* wr1 = wrow1 + base_k;
      #pragma unroll 8
      for (int k4 = 0; k4 < 64; ++k4) {
        float4 cv = *(const float4*)&cr[k4 * 4];
        float4 a  = *(const float4*)&wr0[k4 * 4];
        float4 bb = *(const float4*)&wr1[k4 * 4];
        acc0 += cv.x * a.x  + cv.y * a.y  + cv.z * a.z  + cv.w * a.w;
        acc1 += cv.x * bb.x + cv.y * bb.y + cv.z * bb.z + cv.w * bb.w;
      }
      __syncthreads();
    }
    z[lane * NZ + n0 + j0] = acc0;
    z[lane * NZ + n0 + j1] = acc1;

    grid_barrier(grp_cnt, master, gen, &bar);

    // ---------------- phase B: LN + gates (blocks 0..63) ----------------
    if (blk < B) {
      const int b = blk;
      const float* __restrict__ zb = z + b * NZ;

      float s1 = 0.f, s2 = 0.f;
      #pragma unroll
      for (int i = tid; i < NZ; i += 256) {
        float v = zb[i];
        s1 += v;
        s2 += v * v;
      }
      #pragma unroll
      for (int off = 32; off > 0; off >>= 1) {
        s1 += __shfl_down(s1, off, 64);
        s2 += __shfl_down(s2, off, 64);
      }
      if (lane == 0) { red1[wv] = s1; red2[wv] = s2; }
      __syncthreads();
      float S1 = red1[0] + red1[1] + red1[2] + red1[3];
      float S2 = red2[0] + red2[1] + red2[2] + red2[3];
      float mean = S1 * (1.f / NZ);
      float var  = S2 * (1.f / NZ) - mean * mean;
      float rstd = rsqrtf(var + EPS);

      for (int o = tid; o < O; o += 256) {
        float zf = (zb[o      ] - mean) * rstd * gamma[o      ] + beta[o      ];
        float zi = (zb[O   + o] - mean) * rstd * gamma[O   + o] + beta[O   + o];
        float zo = (zb[2*O + o] - mean) * rstd * gamma[2*O + o] + beta[2*O + o];
        float zg = (zb[3*O + o] - mean) * rstd * gamma[3*O + o] + beta[3*O + o];

        float fg = 1.f / (1.f + expf(-zf));
        float ig = 1.f / (1.f + expf(-zi));
        float og = 1.f / (1.f + expf(-zo));
        float gg = 0.5f * zg * (1.f + erff(zg * 0.70710678118654752f));

        int   ci = b * O + o;
        float cn = fg * c[ci] + ig * gg;
        float hn = og * cn;
        c[ci] = cn;
        h[ci] = hn;
        out[((size_t)b * T + t) * O + o] = hn;
      }
    }

    grid_barrier(grp_cnt, master, gen, &bar);
  }
}

// ---------------------------------------------------------------------------
extern "C" void kernel_launch(void* const* d_in, const int* in_sizes, int n_in,
                              void* d_out, int out_size, void* d_ws, size_t ws_size,
                              hipStream_t stream) {
  const float* x       = (const float*)d_in[0];
  const float* W       = (const float*)d_in[1];
  const float* gamma   = (const float*)d_in[2];
  const float* beta    = (const float*)d_in[3];
  const float* init_hx = (const float*)d_in[4];
  const float* init_cx = (const float*)d_in[5];
  float* out = (float*)d_out;

  unsigned* sync = (unsigned*)d_ws;                       // (NGROUP+2)*32 u32
  float* h = (float*)((char*)d_ws + 4096);                // B*O
  float* c = h + B * O;                                   // B*O
  float* z = c + B * O;                                   // B*NZ
  (void)ws_size; (void)in_sizes; (void)n_in; (void)out_size;

  init_all<<<(B * O + 255) / 256, 256, 0, stream>>>(init_hx, init_cx, h, c, sync);
  lstm_persistent<<<GRID, 256, 0, stream>>>(x, W, gamma, beta, h, c, z, out, sync);
}

// Round 3
// 13980.998 us; speedup vs baseline: 3.0152x; 3.0152x over previous
//
#include <hip/hip_runtime.h>
#include <math.h>

#define B_  64
#define T_  1024
#define I_  512
#define O_  512
#define NZ  2048      // 4*O
#define KW  1024      // W row stride (I+O)
#define EPS 1e-5f

#define SREC 32       // recurrent grid: 32 blocks, each owns 16 o-values
#define OSL  16

typedef short bf8_t  __attribute__((ext_vector_type(8)));
typedef float f32x4  __attribute__((ext_vector_type(4)));

__device__ __forceinline__ unsigned short f2bf(float f) {
  union { float f; unsigned u; } v; v.f = f;
  unsigned r = v.u + 0x7FFFu + ((v.u >> 16) & 1u);   // RNE
  return (unsigned short)(r >> 16);
}
__device__ __forceinline__ float bf2f(unsigned short b) {
  union { unsigned u; float f; } v; v.u = ((unsigned)b) << 16;
  return v.f;
}

// ---------------------------------------------------------------------------
// K0: zero sync counters, init h (bf16) from init_hx
// ---------------------------------------------------------------------------
__global__ __launch_bounds__(256) void init_all(
    const float* __restrict__ init_hx,
    unsigned short* __restrict__ h, unsigned* __restrict__ sync) {
  int idx = blockIdx.x * 256 + threadIdx.x;
  if (idx < 64) sync[idx] = 0u;
  if (idx < B_ * O_) h[idx] = f2bf(init_hx[idx & (O_ - 1)]);
}

// ---------------------------------------------------------------------------
// K1: zx[b*T+t][n] = x[b][t][:] @ Wx[n][:]   (bf16 MFMA, output bf16)
// Block = 256 thr (4 waves), tile 64(M) x 64(N), K=512 in 16 steps of 32.
// Wave w -> m-tile w; n-tiles 0..3 shared across waves (L1 broadcast).
// ---------------------------------------------------------------------------
__global__ __launch_bounds__(256) void zx_gemm(
    const float* __restrict__ x, const float* __restrict__ W,
    unsigned short* __restrict__ zx) {
  const int tid  = threadIdx.x;
  const int w    = tid >> 6;
  const int lane = tid & 63;
  const int q    = lane >> 4;
  const int col  = lane & 15;
  const int mblk = blockIdx.x >> 5;   // 0..1023
  const int nblk = blockIdx.x & 31;   // 0..31
  const int m0   = mblk * 64 + w * 16;
  const int n0   = nblk * 64;

  f32x4 acc[4];
  #pragma unroll
  for (int i = 0; i < 4; ++i) acc[i] = (f32x4){0.f, 0.f, 0.f, 0.f};

  const float* __restrict__ arow = x + (size_t)(m0 + col) * I_;

  for (int ks = 0; ks < 16; ++ks) {
    const int k0 = ks * 32 + q * 8;
    float4 a0 = *(const float4*)(arow + k0);
    float4 a1 = *(const float4*)(arow + k0 + 4);
    bf8_t af;
    af[0] = (short)f2bf(a0.x); af[1] = (short)f2bf(a0.y);
    af[2] = (short)f2bf(a0.z); af[3] = (short)f2bf(a0.w);
    af[4] = (short)f2bf(a1.x); af[5] = (short)f2bf(a1.y);
    af[6] = (short)f2bf(a1.z); af[7] = (short)f2bf(a1.w);
    #pragma unroll
    for (int nt = 0; nt < 4; ++nt) {
      const float* __restrict__ brow =
          W + (size_t)(n0 + nt * 16 + col) * KW + k0;
      float4 b0 = *(const float4*)(brow);
      float4 b1 = *(const float4*)(brow + 4);
      bf8_t bfr;
      bfr[0] = (short)f2bf(b0.x); bfr[1] = (short)f2bf(b0.y);
      bfr[2] = (short)f2bf(b0.z); bfr[3] = (short)f2bf(b0.w);
      bfr[4] = (short)f2bf(b1.x); bfr[5] = (short)f2bf(b1.y);
      bfr[6] = (short)f2bf(b1.z); bfr[7] = (short)f2bf(b1.w);
      acc[nt] = __builtin_amdgcn_mfma_f32_16x16x32_bf16(af, bfr, acc[nt], 0, 0, 0);
    }
  }
  // C/D layout: col = lane&15, row = (lane>>4)*4 + reg  [verified m89]
  #pragma unroll
  for (int nt = 0; nt < 4; ++nt)
    #pragma unroll
    for (int r = 0; r < 4; ++r) {
      int m = m0 + 4 * q + r;
      zx[(size_t)m * NZ + n0 + nt * 16 + col] = f2bf(acc[nt][r]);
    }
}

// ---------------------------------------------------------------------------
// Flat monotonic grid barrier over SREC blocks (round-2 machinery, validated)
// ---------------------------------------------------------------------------
__device__ __forceinline__ void gbar(unsigned* cnt, unsigned* gen, unsigned* bar) {
  __syncthreads();
  if (threadIdx.x == 0) {
    __builtin_amdgcn_fence(__ATOMIC_RELEASE, "agent");
    unsigned old = __hip_atomic_fetch_add(cnt, 1u, __ATOMIC_RELAXED,
                                          __HIP_MEMORY_SCOPE_AGENT);
    if (((old + 1u) & (SREC - 1u)) == 0u)
      __hip_atomic_fetch_add(gen, 1u, __ATOMIC_RELAXED,
                             __HIP_MEMORY_SCOPE_AGENT);
    unsigned target = ++(*bar);
    while (__hip_atomic_load(gen, __ATOMIC_RELAXED,
                             __HIP_MEMORY_SCOPE_AGENT) < target)
      __builtin_amdgcn_s_sleep(1);
    __builtin_amdgcn_fence(__ATOMIC_ACQUIRE, "agent");
  }
  __syncthreads();
}

// ---------------------------------------------------------------------------
// K2: recurrent loop. 32 blocks; block s owns o in [16s,16s+16) across all
// 4 gates (n in {512g+16s..+15}). Wh slice bf16 in LDS (staged once).
// c stays in registers. 2 grid barriers/step.
// ---------------------------------------------------------------------------
__global__ __launch_bounds__(256) void lstm_rec(
    const float* __restrict__ W, const float* __restrict__ gamma,
    const float* __restrict__ beta, const float* __restrict__ init_cx,
    const unsigned short* __restrict__ zx, unsigned short* __restrict__ h,
    float* __restrict__ part, float* __restrict__ out,
    unsigned* __restrict__ sync) {

  __shared__ unsigned short whlds[64 * 520];   // 64 rows (g*16+n'), pad 512->520
  __shared__ float mr[128];                    // mean, rstd per batch row

  const int tid  = threadIdx.x;
  const int w    = tid >> 6;
  const int lane = tid & 63;
  const int q    = lane >> 4;
  const int col  = lane & 15;
  const int s    = blockIdx.x;
  const int o    = s * OSL + col;

  // ---- stage Wh slice -> LDS (once)
  for (int e4 = tid; e4 < 64 * 128; e4 += 256) {
    int r  = e4 >> 7;            // row 0..63
    int k4 = (e4 & 127) * 4;     // k 0..508
    int g  = r >> 4, np = r & 15;
    const float4 v =
        *(const float4*)(W + (size_t)(512 * g + OSL * s + np) * KW + I_ + k4);
    unsigned short* d = &whlds[r * 520 + k4];
    d[0] = f2bf(v.x); d[1] = f2bf(v.y); d[2] = f2bf(v.z); d[3] = f2bf(v.w);
  }

  float gma[4], bta[4], c_reg[4];
  #pragma unroll
  for (int g = 0; g < 4; ++g) { gma[g] = gamma[g * O_ + o]; bta[g] = beta[g * O_ + o]; }
  { float c0 = init_cx[o];
    #pragma unroll
    for (int r = 0; r < 4; ++r) c_reg[r] = c0; }

  unsigned* cnt = sync;
  unsigned* gen = sync + 32;
  unsigned bar = 0;

  __syncthreads();

  for (int t = 0; t < T_; ++t) {
    // ---- prefetch zx (independent of h; overlaps MFMA)
    unsigned short zxl[16];
    #pragma unroll
    for (int g = 0; g < 4; ++g)
      #pragma unroll
      for (int r = 0; r < 4; ++r) {
        int b = 16 * w + 4 * q + r;
        zxl[g * 4 + r] = zx[((size_t)b * T_ + t) * NZ + g * O_ + OSL * s + col];
      }

    // ---- z-slice = h @ Wh^T  (16x16x32 bf16 MFMA; wave w -> rows 16w..16w+15)
    f32x4 acc[4];
    #pragma unroll
    for (int g = 0; g < 4; ++g) acc[g] = (f32x4){0.f, 0.f, 0.f, 0.f};

    const unsigned short* __restrict__ hrow = h + (16 * w + col) * O_;
    #pragma unroll
    for (int ks = 0; ks < 16; ++ks) {
      bf8_t af = *(const bf8_t*)(hrow + ks * 32 + q * 8);
      #pragma unroll
      for (int g = 0; g < 4; ++g) {
        bf8_t bfr = *(const bf8_t*)(&whlds[(g * 16 + col) * 520 + ks * 32 + q * 8]);
        acc[g] = __builtin_amdgcn_mfma_f32_16x16x32_bf16(af, bfr, acc[g], 0, 0, 0);
      }
    }

    // ---- z = acc + zx; block-partial LN sums per batch row
    float z[16];
    float s1[4], s2[4];
    #pragma unroll
    for (int r = 0; r < 4; ++r) { s1[r] = 0.f; s2[r] = 0.f; }
    #pragma unroll
    for (int g = 0; g < 4; ++g)
      #pragma unroll
      for (int r = 0; r < 4; ++r) {
        float zv = acc[g][r] + bf2f(zxl[g * 4 + r]);
        z[g * 4 + r] = zv;
        s1[r] += zv;
        s2[r] += zv * zv;
      }
    #pragma unroll
    for (int m = 1; m < 16; m <<= 1) {
      #pragma unroll
      for (int r = 0; r < 4; ++r) {
        s1[r] += __shfl_xor(s1[r], m, 64);
        s2[r] += __shfl_xor(s2[r], m, 64);
      }
    }
    if (col == 0) {
      #pragma unroll
      for (int r = 0; r < 4; ++r) {
        int b = 16 * w + 4 * q + r;
        part[(b * SREC + s) * 2 + 0] = s1[r];
        part[(b * SREC + s) * 2 + 1] = s2[r];
      }
    }

    gbar(cnt, gen, &bar);

    // ---- reduce partials -> mean, rstd (wave 0: one thread per batch row)
    if (tid < 64) {
      const float4* p = (const float4*)(part + tid * (SREC * 2));
      float S1 = 0.f, S2 = 0.f;
      #pragma unroll
      for (int i = 0; i < 16; ++i) {
        float4 v = p[i];
        S1 += v.x + v.z;
        S2 += v.y + v.w;
      }
      float mean = S1 * (1.f / NZ);
      float var  = S2 * (1.f / NZ) - mean * mean;
      mr[2 * tid]     = mean;
      mr[2 * tid + 1] = rsqrtf(var + EPS);
    }
    __syncthreads();

    // ---- gates + state update (all 4 gates of (b,o) live in this lane)
    #pragma unroll
    for (int r = 0; r < 4; ++r) {
      int b = 16 * w + 4 * q + r;
      float mean = mr[2 * b], rstd = mr[2 * b + 1];
      float zn0 = (z[0 * 4 + r] - mean) * rstd * gma[0] + bta[0];
      float zn1 = (z[1 * 4 + r] - mean) * rstd * gma[1] + bta[1];
      float zn2 = (z[2 * 4 + r] - mean) * rstd * gma[2] + bta[2];
      float zn3 = (z[3 * 4 + r] - mean) * rstd * gma[3] + bta[3];
      float fg = 1.f / (1.f + expf(-zn0));
      float ig = 1.f / (1.f + expf(-zn1));
      float og = 1.f / (1.f + expf(-zn2));
      float gg = 0.5f * zn3 * (1.f + erff(zn3 * 0.70710678118654752f));
      float cn = fg * c_reg[r] + ig * gg;
      float hn = og * cn;
      c_reg[r] = cn;
      h[b * O_ + o] = f2bf(hn);
      out[((size_t)b * T_ + t) * O_ + o] = hn;
    }

    gbar(cnt, gen, &bar);
  }
}

// ---------------------------------------------------------------------------
extern "C" void kernel_launch(void* const* d_in, const int* in_sizes, int n_in,
                              void* d_out, int out_size, void* d_ws, size_t ws_size,
                              hipStream_t stream) {
  const float* x       = (const float*)d_in[0];
  const float* W       = (const float*)d_in[1];
  const float* gamma   = (const float*)d_in[2];
  const float* beta    = (const float*)d_in[3];
  const float* init_hx = (const float*)d_in[4];
  const float* init_cx = (const float*)d_in[5];
  float* out = (float*)d_out;
  (void)in_sizes; (void)n_in; (void)out_size; (void)ws_size;

  char* ws = (char*)d_ws;
  unsigned*       sync = (unsigned*)(ws);                        // 256 B
  float*          part = (float*)(ws + 1024);                    // 16 KB
  unsigned short* h    = (unsigned short*)(ws + 1024 + 16384);   // 64 KB
  unsigned short* zx   = (unsigned short*)(ws + (1 << 20));      // 256 MB

  init_all<<<128, 256, 0, stream>>>(init_hx, h, sync);
  zx_gemm<<<32768, 256, 0, stream>>>(x, W, zx);
  lstm_rec<<<SREC, 256, 0, stream>>>(W, gamma, beta, init_cx, zx, h, part, out, sync);
}